// Round 5
// baseline (7824.734 us; speedup 1.0000x reference)
//
#include <hip/hip_runtime.h>

#define NFEAT 256
#define BM 64
#define BN 64
#define BK 16

// o = a + b + c (elementwise), n elements (folded twin weights)
__global__ __launch_bounds__(256) void addw3_kernel(const float* __restrict__ a,
                                                    const float* __restrict__ b,
                                                    const float* __restrict__ c,
                                                    float* __restrict__ o, int n) {
    int i = blockIdx.x * 256 + threadIdx.x;
    if (i < n) o[i] = a[i] + b[i] + c[i];
}

__global__ __launch_bounds__(256) void deg_kernel(const int* __restrict__ dst,
                                                  float* __restrict__ deg, int nE) {
    int e = blockIdx.x * 256 + threadIdx.x;
    if (e < nE) atomicAdd(&deg[dst[e]], 1.0f);
}

// per edge: D[dst] += T[src] / deg[dst]   (wave per edge, float4 per lane)
__global__ __launch_bounds__(256) void scatter_mean_kernel(const float* __restrict__ T,
                                                           const int* __restrict__ src,
                                                           const int* __restrict__ dst,
                                                           const float* __restrict__ deg,
                                                           float* __restrict__ D, int nE) {
    int e = blockIdx.x * 4 + (threadIdx.x >> 6);
    if (e >= nE) return;
    int lane = threadIdx.x & 63;
    int s = src[e], d = dst[e];
    float inv = 1.0f / deg[d];   // deg >= 1 whenever an edge exists
    float4 v = ((const float4*)(T + (size_t)s * NFEAT))[lane];
    float* Dd = D + (size_t)d * NFEAT + lane * 4;
    atomicAdd(Dd + 0, v.x * inv);
    atomicAdd(Dd + 1, v.y * inv);
    atomicAdd(Dd + 2, v.z * inv);
    atomicAdd(Dd + 3, v.w * inv);
}

// in-place relu, n4 float4s
__global__ __launch_bounds__(256) void relu_kernel(float* __restrict__ A, int n4) {
    int i = blockIdx.x * 256 + threadIdx.x;
    if (i >= n4) return;
    float4 v = ((float4*)A)[i];
    v.x = fmaxf(v.x, 0.f); v.y = fmaxf(v.y, 0.f);
    v.z = fmaxf(v.z, 0.f); v.w = fmaxf(v.w, 0.f);
    ((float4*)A)[i] = v;
}

// s[n] = dot(A[n,:], B[n,:]) over 256 feats; 4 nodes per 256-thread block
__global__ __launch_bounds__(256) void rowdot_kernel(const float* __restrict__ A,
                                                     const float* __restrict__ B,
                                                     float* __restrict__ s, int M) {
    int n = blockIdx.x * 4 + (threadIdx.x >> 6);
    if (n >= M) return;
    int lane = threadIdx.x & 63;
    float4 a = ((const float4*)(A + (size_t)n * NFEAT))[lane];
    float4 b = ((const float4*)(B + (size_t)n * NFEAT))[lane];
    float d = a.x * b.x + a.y * b.y + a.z * b.z + a.w * b.w;
    #pragma unroll
    for (int off = 32; off > 0; off >>= 1) d += __shfl_down(d, off);
    if (lane == 0) s[n] = d;
}

// per node: softmax(s0,s1) -> alpha (fp32); h = a0*P1 + a1*P2 (fp32)
__global__ __launch_bounds__(256) void combine_kernel(const float* __restrict__ P1,
                                                      const float* __restrict__ P2,
                                                      const float* __restrict__ s0,
                                                      const float* __restrict__ s1,
                                                      float* __restrict__ h,
                                                      float* __restrict__ alpha,
                                                      int M) {
    int n = blockIdx.x * 4 + (threadIdx.x >> 6);
    if (n >= M) return;
    int lane = threadIdx.x & 63;
    float v0 = s0[n], v1 = s1[n];
    float m = fmaxf(v0, v1);
    float e0 = expf(v0 - m), e1 = expf(v1 - m);
    float inv = 1.0f / (e0 + e1);
    float a0 = e0 * inv, a1 = e1 * inv;
    float4 p1 = ((const float4*)(P1 + (size_t)n * NFEAT))[lane];
    float4 p2 = ((const float4*)(P2 + (size_t)n * NFEAT))[lane];
    float4 hv;
    hv.x = a0 * p1.x + a1 * p2.x;
    hv.y = a0 * p1.y + a1 * p2.y;
    hv.z = a0 * p1.z + a1 * p2.z;
    hv.w = a0 * p1.w + a1 * p2.w;
    ((float4*)(h + (size_t)n * NFEAT))[lane] = hv;
    if (lane == 0) {
        alpha[n]     = a0;
        alpha[M + n] = a1;
    }
}

// C[M,N] = maybe_relu(X[M,256] @ W[256,N] + maybe_bias); all fp32
__global__ __launch_bounds__(256) void gemm_k(
    const float* __restrict__ X, const float* __restrict__ W,
    const float* __restrict__ bias, int do_relu,
    float* __restrict__ C, int M, int N)
{
    __shared__ float Xs[BK][BM];  // transposed X tile: Xs[k][row]
    __shared__ float Ws[BK][BN];

    int tid = threadIdx.x;
    int row0 = blockIdx.x * BM, col0 = blockIdx.y * BN;

    int lr = tid & 63;
    int lk = (tid >> 6) * 4;
    int wk = tid >> 4;
    int wc = (tid & 15) * 4;
    int ty = tid >> 4;
    int tx = tid & 15;

    int grow = row0 + lr;
    if (grow >= M) grow = M - 1;  // clamp; stores guarded

    float acc[4][4] = {{0.f}};

    for (int k0 = 0; k0 < NFEAT; k0 += BK) {
        float4 xv = *(const float4*)(X + (size_t)grow * NFEAT + k0 + lk);
        float4 wv = *(const float4*)(W + (size_t)(k0 + wk) * N + col0 + wc);
        __syncthreads();
        Xs[lk + 0][lr] = xv.x;
        Xs[lk + 1][lr] = xv.y;
        Xs[lk + 2][lr] = xv.z;
        Xs[lk + 3][lr] = xv.w;
        *(float4*)&Ws[wk][wc] = wv;
        __syncthreads();
        #pragma unroll
        for (int kk = 0; kk < BK; ++kk) {
            float4 a = *(const float4*)&Xs[kk][ty * 4];
            float4 b = *(const float4*)&Ws[kk][tx * 4];
            acc[0][0] += a.x * b.x; acc[0][1] += a.x * b.y;
            acc[0][2] += a.x * b.z; acc[0][3] += a.x * b.w;
            acc[1][0] += a.y * b.x; acc[1][1] += a.y * b.y;
            acc[1][2] += a.y * b.z; acc[1][3] += a.y * b.w;
            acc[2][0] += a.z * b.x; acc[2][1] += a.z * b.y;
            acc[2][2] += a.z * b.z; acc[2][3] += a.z * b.w;
            acc[3][0] += a.w * b.x; acc[3][1] += a.w * b.y;
            acc[3][2] += a.w * b.z; acc[3][3] += a.w * b.w;
        }
    }

    #pragma unroll
    for (int i = 0; i < 4; ++i) {
        int r = row0 + ty * 4 + i;
        if (r >= M) continue;
        int c0 = col0 + tx * 4;
        #pragma unroll
        for (int j = 0; j < 4; ++j) {
            float v = acc[i][j];
            if (bias) v += bias[c0 + j];
            if (do_relu) v = fmaxf(v, 0.0f);
            C[(size_t)r * N + c0 + j] = v;
        }
    }
}

// s[r] = dot( relu(X[r,:]@W + bias), P[r,:] ), all fp32 — never materializes the GEMM
__global__ __launch_bounds__(256) void gemm_rowdot_kernel(
    const float* __restrict__ X, const float* __restrict__ W,
    const float* __restrict__ bias, const float* __restrict__ P,
    float* __restrict__ s, int M)
{
    __shared__ float Xs[BK][BM];
    __shared__ float Ws[BK][BN];
    __shared__ float srow[BM];

    int tid = threadIdx.x;
    int row0 = blockIdx.x * BM;

    int lr = tid & 63;
    int lk = (tid >> 6) * 4;
    int wk = tid >> 4;
    int wc = (tid & 15) * 4;
    int ty = tid >> 4;
    int tx = tid & 15;

    int grow = row0 + lr;
    if (grow >= M) grow = M - 1;

    if (tid < BM) srow[tid] = 0.f;

    float rp[4] = {0.f, 0.f, 0.f, 0.f};

    for (int col0 = 0; col0 < NFEAT; col0 += BN) {
        float acc[4][4] = {{0.f}};
        for (int k0 = 0; k0 < NFEAT; k0 += BK) {
            float4 xv = *(const float4*)(X + (size_t)grow * NFEAT + k0 + lk);
            float4 wv = *(const float4*)(W + (size_t)(k0 + wk) * NFEAT + col0 + wc);
            __syncthreads();
            Xs[lk + 0][lr] = xv.x;
            Xs[lk + 1][lr] = xv.y;
            Xs[lk + 2][lr] = xv.z;
            Xs[lk + 3][lr] = xv.w;
            *(float4*)&Ws[wk][wc] = wv;
            __syncthreads();
            #pragma unroll
            for (int kk = 0; kk < BK; ++kk) {
                float4 a = *(const float4*)&Xs[kk][ty * 4];
                float4 b = *(const float4*)&Ws[kk][tx * 4];
                acc[0][0] += a.x * b.x; acc[0][1] += a.x * b.y;
                acc[0][2] += a.x * b.z; acc[0][3] += a.x * b.w;
                acc[1][0] += a.y * b.x; acc[1][1] += a.y * b.y;
                acc[1][2] += a.y * b.z; acc[1][3] += a.y * b.w;
                acc[2][0] += a.z * b.x; acc[2][1] += a.z * b.y;
                acc[2][2] += a.z * b.z; acc[2][3] += a.z * b.w;
                acc[3][0] += a.w * b.x; acc[3][1] += a.w * b.y;
                acc[3][2] += a.w * b.z; acc[3][3] += a.w * b.w;
            }
        }
        int c0 = col0 + tx * 4;
        #pragma unroll
        for (int i = 0; i < 4; ++i) {
            int r = row0 + ty * 4 + i;
            if (r >= M) continue;
            float4 p = *(const float4*)(P + (size_t)r * NFEAT + c0);
            float v0 = fmaxf(acc[i][0] + bias[c0 + 0], 0.f);
            float v1 = fmaxf(acc[i][1] + bias[c0 + 1], 0.f);
            float v2 = fmaxf(acc[i][2] + bias[c0 + 2], 0.f);
            float v3 = fmaxf(acc[i][3] + bias[c0 + 3], 0.f);
            rp[i] += v0 * p.x + v1 * p.y + v2 * p.z + v3 * p.w;
        }
    }
    __syncthreads();
    #pragma unroll
    for (int i = 0; i < 4; ++i) atomicAdd(&srow[ty * 4 + i], rp[i]);
    __syncthreads();
    if (tid < BM && row0 + tid < M) s[row0 + tid] = srow[tid];
}

extern "C" void kernel_launch(void* const* d_in, const int* in_sizes, int n_in,
                              void* d_out, int out_size, void* d_ws, size_t ws_size,
                              hipStream_t stream)
{
    // All float tensors are fp32 (per the reference); indices int32. Output fp32.
    const float* x_paper    = (const float*)d_in[0];
    const float* emb_author = (const float*)d_in[1];
    const float* W0rp = (const float*)d_in[2];
    const float* b0rp = (const float*)d_in[3];
    const float* W0ra = (const float*)d_in[4];
    const float* b0ra = (const float*)d_in[5];
    const float* W0w  = (const float*)d_in[6];
    const float* W0rev= (const float*)d_in[7];
    const float* W0c  = (const float*)d_in[8];
    const float* W1rp = (const float*)d_in[9];
    const float* b1rp = (const float*)d_in[10];
    const float* W1w  = (const float*)d_in[13];
    const float* W1c  = (const float*)d_in[15];
    const float* outW = (const float*)d_in[16];
    const float* outb = (const float*)d_in[17];
    const int* w_src = (const int*)d_in[18];
    const int* w_dst = (const int*)d_in[19];
    const int* r_src = (const int*)d_in[20];
    const int* r_dst = (const int*)d_in[21];
    const int* c_src = (const int*)d_in[22];
    const int* c_dst = (const int*)d_in[23];

    const int NP = in_sizes[0] / NFEAT;   // 50000
    const int NA = in_sizes[1] / NFEAT;   // 50000
    const int NC = in_sizes[17];          // 128
    const int nEw = in_sizes[18], nEr = in_sizes[20], nEc = in_sizes[22];

    // workspace (fp32): 3 big node buffers + small tails ~= 155 MB (known-safe)
    size_t NB = (size_t)(NP > NA ? NP : NA) * NFEAT;
    float* Z1 = (float*)d_ws;       // P1 (lives to the end)
    float* Z2 = Z1 + NB;            // T / Au1 / P2
    float* Z3 = Z2 + NB;            // T / P1t / h
    float* degW = Z3 + NB;          // NP
    float* degR = degW + NP;        // NA
    float* degC = degR + NA;        // NP
    float* s0   = degC + NP;        // NP
    float* s1   = s0 + NP;          // NP
    float* Wc0  = s1 + NP;          // 256*256: W0rp+W0w+W0c
    float* Wc1  = Wc0 + NFEAT * NFEAT;

    float* out   = (float*)d_out;                 // logits [NP, NC]
    float* alpha = out + (size_t)NP * NC;         // [2, NP]

    hipMemsetAsync(degW, 0, (size_t)(NP + NA + NP) * sizeof(float), stream);

    deg_kernel<<<(nEw + 255) / 256, 256, 0, stream>>>(w_dst, degW, nEw);
    deg_kernel<<<(nEr + 255) / 256, 256, 0, stream>>>(r_dst, degR, nEr);
    deg_kernel<<<(nEc + 255) / 256, 256, 0, stream>>>(c_dst, degC, nEc);

    int nW = NFEAT * NFEAT;
    addw3_kernel<<<(nW + 255) / 256, 256, 0, stream>>>(W0rp, W0w, W0c, Wc0, nW);
    addw3_kernel<<<(nW + 255) / 256, 256, 0, stream>>>(W1rp, W1w, W1c, Wc1, nW);

    dim3 blk(256);
    dim3 gP((NP + BM - 1) / BM, NFEAT / BN);
    dim3 gA((NA + BM - 1) / BM, NFEAT / BN);
    dim3 gR((NP + BM - 1) / BM);
    int n4p = NP * (NFEAT / 4);
    int relu_blocks = (n4p + 255) / 256;
    int node4 = (NP + 3) / 4;

    // --- L0 paper: P1 = relu(Xp@W0rp + b + mean_w(Xa@W0w) + mean_c(Xp@W0c)) ---
    gemm_k<<<gP, blk, 0, stream>>>(x_paper, W0rp, b0rp, 0, Z1, NP, NFEAT);
    gemm_k<<<gA, blk, 0, stream>>>(emb_author, W0w, nullptr, 0, Z2, NA, NFEAT);
    scatter_mean_kernel<<<(nEw + 3) / 4, blk, 0, stream>>>(Z2, w_src, w_dst, degW, Z1, nEw);
    gemm_k<<<gP, blk, 0, stream>>>(x_paper, W0c, nullptr, 0, Z2, NP, NFEAT);
    scatter_mean_kernel<<<(nEc + 3) / 4, blk, 0, stream>>>(Z2, c_src, c_dst, degC, Z1, nEc);
    relu_kernel<<<relu_blocks, blk, 0, stream>>>(Z1, n4p);                 // P1 in Z1

    // --- L0 author: Au1 = relu(Xa@W0ra + b + mean_rev(Xp@W0rev)) ---
    gemm_k<<<gA, blk, 0, stream>>>(emb_author, W0ra, b0ra, 0, Z2, NA, NFEAT);
    gemm_k<<<gP, blk, 0, stream>>>(x_paper, W0rev, nullptr, 0, Z3, NP, NFEAT);
    scatter_mean_kernel<<<(nEr + 3) / 4, blk, 0, stream>>>(Z3, r_src, r_dst, degR, Z2, nEr);
    relu_kernel<<<relu_blocks, blk, 0, stream>>>(Z2, NA * (NFEAT / 4));    // Au1 in Z2

    // --- L1 paper: P2 = relu(P1@W1rp + b + mean_w(Au1@W1w) + mean_c(P1@W1c)) ---
    gemm_k<<<gA, blk, 0, stream>>>(Z2, W1w, nullptr, 0, Z3, NA, NFEAT);    // T = Au1@W1w
    gemm_k<<<gP, blk, 0, stream>>>(Z1, W1rp, b1rp, 0, Z2, NP, NFEAT);      // P2pre (Au1 consumed)
    scatter_mean_kernel<<<(nEw + 3) / 4, blk, 0, stream>>>(Z3, w_src, w_dst, degW, Z2, nEw);
    gemm_k<<<gP, blk, 0, stream>>>(Z1, W1c, nullptr, 0, Z3, NP, NFEAT);    // T = P1@W1c
    scatter_mean_kernel<<<(nEc + 3) / 4, blk, 0, stream>>>(Z3, c_src, c_dst, degC, Z2, nEc);
    relu_kernel<<<relu_blocks, blk, 0, stream>>>(Z2, n4p);                 // P2 in Z2

    // --- twin path: P1t in Z3; P2t fused into rowdot ---
    gemm_k<<<gP, blk, 0, stream>>>(x_paper, Wc0, b0rp, 1, Z3, NP, NFEAT);  // P1t
    rowdot_kernel<<<node4, blk, 0, stream>>>(Z1, Z3, s0, NP);              // s0 = P1·P1t
    gemm_rowdot_kernel<<<gR, blk, 0, stream>>>(Z3, Wc1, b1rp, Z2, s1, NP); // s1 = P2·relu(P1t@Wc1+b)

    // --- summarize + head ---
    combine_kernel<<<node4, blk, 0, stream>>>(Z1, Z2, s0, s1, Z3, alpha, NP); // h in Z3
    dim3 gO((NP + BM - 1) / BM, NC / BN);
    gemm_k<<<gO, blk, 0, stream>>>(Z3, outW, outb, 0, out, NP, NC);
}

// Round 6
// 1767.806 us; speedup vs baseline: 4.4262x; 4.4262x over previous
//
#include <hip/hip_runtime.h>

#define NFEAT 256
#define BM 64
#define BN 64
#define BK 16

// o = a + b + c (elementwise), n elements (folded twin weights)
__global__ __launch_bounds__(256) void addw3_kernel(const float* __restrict__ a,
                                                    const float* __restrict__ b,
                                                    const float* __restrict__ c,
                                                    float* __restrict__ o, int n) {
    int i = blockIdx.x * 256 + threadIdx.x;
    if (i < n) o[i] = a[i] + b[i] + c[i];
}

__global__ __launch_bounds__(256) void deg_int_kernel(const int* __restrict__ dst,
                                                      int* __restrict__ deg, int nE) {
    int e = blockIdx.x * 256 + threadIdx.x;
    if (e < nE) atomicAdd(&deg[dst[e]], 1);
}

// 3 independent exclusive prefix sums (one block each): off[0]=0, off[i+1]=sum(deg[0..i])
__global__ __launch_bounds__(256) void scan3_kernel(const int* __restrict__ dA, int nA, int* __restrict__ oA,
                                                    const int* __restrict__ dB, int nB, int* __restrict__ oB,
                                                    const int* __restrict__ dC, int nC, int* __restrict__ oC) {
    const int* deg; int n; int* off;
    if (blockIdx.x == 0) { deg = dA; n = nA; off = oA; }
    else if (blockIdx.x == 1) { deg = dB; n = nB; off = oB; }
    else { deg = dC; n = nC; off = oC; }

    __shared__ int tmp[256];
    int tid = threadIdx.x;
    int carry = 0;
    for (int base = 0; base < n; base += 256) {
        int i = base + tid;
        tmp[tid] = (i < n) ? deg[i] : 0;
        __syncthreads();
        #pragma unroll
        for (int ofs = 1; ofs < 256; ofs <<= 1) {
            int t = (tid >= ofs) ? tmp[tid - ofs] : 0;
            __syncthreads();
            tmp[tid] += t;
            __syncthreads();
        }
        if (i < n) off[i + 1] = carry + tmp[tid];
        carry += tmp[255];
        __syncthreads();
    }
    if (tid == 0) off[0] = 0;
}

// list[off[dst]+pos] = src  (pos via per-dst cursor)
__global__ __launch_bounds__(256) void fill_csr_kernel(const int* __restrict__ src,
                                                       const int* __restrict__ dst, int nE,
                                                       const int* __restrict__ off,
                                                       int* __restrict__ cursor,
                                                       int* __restrict__ list) {
    int e = blockIdx.x * 256 + threadIdx.x;
    if (e >= nE) return;
    int d = dst[e];
    int pos = atomicAdd(&cursor[d], 1);
    list[off[d] + pos] = src[e];
}

// per dst row r: D[r,:] += mean over incoming edges of T[src,:]; optional fused relu.
// one wave per row, lane handles one float4; no atomics (row ownership exclusive).
__global__ __launch_bounds__(256) void agg_csr_kernel(const float* __restrict__ T,
                                                      const int* __restrict__ off,
                                                      const int* __restrict__ list,
                                                      float* __restrict__ D,
                                                      int do_relu, int M) {
    int r = blockIdx.x * 4 + (threadIdx.x >> 6);
    if (r >= M) return;
    int lane = threadIdx.x & 63;
    int start = off[r], end = off[r + 1];
    float4 acc = make_float4(0.f, 0.f, 0.f, 0.f);
    for (int e = start; e < end; ++e) {
        int s = list[e];
        float4 v = ((const float4*)(T + (size_t)s * NFEAT))[lane];
        acc.x += v.x; acc.y += v.y; acc.z += v.z; acc.w += v.w;
    }
    int cnt = end - start;
    float inv = (cnt > 0) ? 1.0f / (float)cnt : 0.0f;
    float4 d = ((float4*)(D + (size_t)r * NFEAT))[lane];
    d.x += acc.x * inv; d.y += acc.y * inv;
    d.z += acc.z * inv; d.w += acc.w * inv;
    if (do_relu) {
        d.x = fmaxf(d.x, 0.f); d.y = fmaxf(d.y, 0.f);
        d.z = fmaxf(d.z, 0.f); d.w = fmaxf(d.w, 0.f);
    }
    ((float4*)(D + (size_t)r * NFEAT))[lane] = d;
}

// s[n] = dot(A[n,:], B[n,:]) over 256 feats; 4 nodes per 256-thread block
__global__ __launch_bounds__(256) void rowdot_kernel(const float* __restrict__ A,
                                                     const float* __restrict__ B,
                                                     float* __restrict__ s, int M) {
    int n = blockIdx.x * 4 + (threadIdx.x >> 6);
    if (n >= M) return;
    int lane = threadIdx.x & 63;
    float4 a = ((const float4*)(A + (size_t)n * NFEAT))[lane];
    float4 b = ((const float4*)(B + (size_t)n * NFEAT))[lane];
    float d = a.x * b.x + a.y * b.y + a.z * b.z + a.w * b.w;
    #pragma unroll
    for (int off = 32; off > 0; off >>= 1) d += __shfl_down(d, off);
    if (lane == 0) s[n] = d;
}

// per node: softmax(s0,s1) -> alpha; h = a0*P1 + a1*P2 (all fp32)
__global__ __launch_bounds__(256) void combine_kernel(const float* __restrict__ P1,
                                                      const float* __restrict__ P2,
                                                      const float* __restrict__ s0,
                                                      const float* __restrict__ s1,
                                                      float* __restrict__ h,
                                                      float* __restrict__ alpha,
                                                      int M) {
    int n = blockIdx.x * 4 + (threadIdx.x >> 6);
    if (n >= M) return;
    int lane = threadIdx.x & 63;
    float v0 = s0[n], v1 = s1[n];
    float m = fmaxf(v0, v1);
    float e0 = expf(v0 - m), e1 = expf(v1 - m);
    float inv = 1.0f / (e0 + e1);
    float a0 = e0 * inv, a1 = e1 * inv;
    float4 p1 = ((const float4*)(P1 + (size_t)n * NFEAT))[lane];
    float4 p2 = ((const float4*)(P2 + (size_t)n * NFEAT))[lane];
    float4 hv;
    hv.x = a0 * p1.x + a1 * p2.x;
    hv.y = a0 * p1.y + a1 * p2.y;
    hv.z = a0 * p1.z + a1 * p2.z;
    hv.w = a0 * p1.w + a1 * p2.w;
    ((float4*)(h + (size_t)n * NFEAT))[lane] = hv;
    if (lane == 0) {
        alpha[n]     = a0;
        alpha[M + n] = a1;
    }
}

// C[M,N] = maybe_relu(X[M,256] @ W[256,N] + maybe_bias); all fp32
__global__ __launch_bounds__(256) void gemm_k(
    const float* __restrict__ X, const float* __restrict__ W,
    const float* __restrict__ bias, int do_relu,
    float* __restrict__ C, int M, int N)
{
    __shared__ float Xs[BK][BM];  // transposed X tile: Xs[k][row]
    __shared__ float Ws[BK][BN];

    int tid = threadIdx.x;
    int row0 = blockIdx.x * BM, col0 = blockIdx.y * BN;

    int lr = tid & 63;
    int lk = (tid >> 6) * 4;
    int wk = tid >> 4;
    int wc = (tid & 15) * 4;
    int ty = tid >> 4;
    int tx = tid & 15;

    int grow = row0 + lr;
    if (grow >= M) grow = M - 1;  // clamp; stores guarded

    float acc[4][4] = {{0.f}};

    for (int k0 = 0; k0 < NFEAT; k0 += BK) {
        float4 xv = *(const float4*)(X + (size_t)grow * NFEAT + k0 + lk);
        float4 wv = *(const float4*)(W + (size_t)(k0 + wk) * N + col0 + wc);
        __syncthreads();
        Xs[lk + 0][lr] = xv.x;
        Xs[lk + 1][lr] = xv.y;
        Xs[lk + 2][lr] = xv.z;
        Xs[lk + 3][lr] = xv.w;
        *(float4*)&Ws[wk][wc] = wv;
        __syncthreads();
        #pragma unroll
        for (int kk = 0; kk < BK; ++kk) {
            float4 a = *(const float4*)&Xs[kk][ty * 4];
            float4 b = *(const float4*)&Ws[kk][tx * 4];
            acc[0][0] += a.x * b.x; acc[0][1] += a.x * b.y;
            acc[0][2] += a.x * b.z; acc[0][3] += a.x * b.w;
            acc[1][0] += a.y * b.x; acc[1][1] += a.y * b.y;
            acc[1][2] += a.y * b.z; acc[1][3] += a.y * b.w;
            acc[2][0] += a.z * b.x; acc[2][1] += a.z * b.y;
            acc[2][2] += a.z * b.z; acc[2][3] += a.z * b.w;
            acc[3][0] += a.w * b.x; acc[3][1] += a.w * b.y;
            acc[3][2] += a.w * b.z; acc[3][3] += a.w * b.w;
        }
    }

    #pragma unroll
    for (int i = 0; i < 4; ++i) {
        int r = row0 + ty * 4 + i;
        if (r >= M) continue;
        int c0 = col0 + tx * 4;
        #pragma unroll
        for (int j = 0; j < 4; ++j) {
            float v = acc[i][j];
            if (bias) v += bias[c0 + j];
            if (do_relu) v = fmaxf(v, 0.0f);
            C[(size_t)r * N + c0 + j] = v;
        }
    }
}

// s[r] = dot( relu(X[r,:]@W + bias), P[r,:] ), all fp32 — never materializes the GEMM
__global__ __launch_bounds__(256) void gemm_rowdot_kernel(
    const float* __restrict__ X, const float* __restrict__ W,
    const float* __restrict__ bias, const float* __restrict__ P,
    float* __restrict__ s, int M)
{
    __shared__ float Xs[BK][BM];
    __shared__ float Ws[BK][BN];
    __shared__ float srow[BM];

    int tid = threadIdx.x;
    int row0 = blockIdx.x * BM;

    int lr = tid & 63;
    int lk = (tid >> 6) * 4;
    int wk = tid >> 4;
    int wc = (tid & 15) * 4;
    int ty = tid >> 4;
    int tx = tid & 15;

    int grow = row0 + lr;
    if (grow >= M) grow = M - 1;

    if (tid < BM) srow[tid] = 0.f;

    float rp[4] = {0.f, 0.f, 0.f, 0.f};

    for (int col0 = 0; col0 < NFEAT; col0 += BN) {
        float acc[4][4] = {{0.f}};
        for (int k0 = 0; k0 < NFEAT; k0 += BK) {
            float4 xv = *(const float4*)(X + (size_t)grow * NFEAT + k0 + lk);
            float4 wv = *(const float4*)(W + (size_t)(k0 + wk) * NFEAT + col0 + wc);
            __syncthreads();
            Xs[lk + 0][lr] = xv.x;
            Xs[lk + 1][lr] = xv.y;
            Xs[lk + 2][lr] = xv.z;
            Xs[lk + 3][lr] = xv.w;
            *(float4*)&Ws[wk][wc] = wv;
            __syncthreads();
            #pragma unroll
            for (int kk = 0; kk < BK; ++kk) {
                float4 a = *(const float4*)&Xs[kk][ty * 4];
                float4 b = *(const float4*)&Ws[kk][tx * 4];
                acc[0][0] += a.x * b.x; acc[0][1] += a.x * b.y;
                acc[0][2] += a.x * b.z; acc[0][3] += a.x * b.w;
                acc[1][0] += a.y * b.x; acc[1][1] += a.y * b.y;
                acc[1][2] += a.y * b.z; acc[1][3] += a.y * b.w;
                acc[2][0] += a.z * b.x; acc[2][1] += a.z * b.y;
                acc[2][2] += a.z * b.z; acc[2][3] += a.z * b.w;
                acc[3][0] += a.w * b.x; acc[3][1] += a.w * b.y;
                acc[3][2] += a.w * b.z; acc[3][3] += a.w * b.w;
            }
        }
        int c0 = col0 + tx * 4;
        #pragma unroll
        for (int i = 0; i < 4; ++i) {
            int r = row0 + ty * 4 + i;
            if (r >= M) continue;
            float4 p = *(const float4*)(P + (size_t)r * NFEAT + c0);
            float v0 = fmaxf(acc[i][0] + bias[c0 + 0], 0.f);
            float v1 = fmaxf(acc[i][1] + bias[c0 + 1], 0.f);
            float v2 = fmaxf(acc[i][2] + bias[c0 + 2], 0.f);
            float v3 = fmaxf(acc[i][3] + bias[c0 + 3], 0.f);
            rp[i] += v0 * p.x + v1 * p.y + v2 * p.z + v3 * p.w;
        }
    }
    __syncthreads();
    #pragma unroll
    for (int i = 0; i < 4; ++i) atomicAdd(&srow[ty * 4 + i], rp[i]);
    __syncthreads();
    if (tid < BM && row0 + tid < M) s[row0 + tid] = srow[tid];
}

extern "C" void kernel_launch(void* const* d_in, const int* in_sizes, int n_in,
                              void* d_out, int out_size, void* d_ws, size_t ws_size,
                              hipStream_t stream)
{
    const float* x_paper    = (const float*)d_in[0];
    const float* emb_author = (const float*)d_in[1];
    const float* W0rp = (const float*)d_in[2];
    const float* b0rp = (const float*)d_in[3];
    const float* W0ra = (const float*)d_in[4];
    const float* b0ra = (const float*)d_in[5];
    const float* W0w  = (const float*)d_in[6];
    const float* W0rev= (const float*)d_in[7];
    const float* W0c  = (const float*)d_in[8];
    const float* W1rp = (const float*)d_in[9];
    const float* b1rp = (const float*)d_in[10];
    const float* W1w  = (const float*)d_in[13];
    const float* W1c  = (const float*)d_in[15];
    const float* outW = (const float*)d_in[16];
    const float* outb = (const float*)d_in[17];
    const int* w_src = (const int*)d_in[18];
    const int* w_dst = (const int*)d_in[19];
    const int* r_src = (const int*)d_in[20];
    const int* r_dst = (const int*)d_in[21];
    const int* c_src = (const int*)d_in[22];
    const int* c_dst = (const int*)d_in[23];

    const int NP = in_sizes[0] / NFEAT;   // 50000
    const int NA = in_sizes[1] / NFEAT;   // 50000
    const int NC = in_sizes[17];          // 128
    const int nEw = in_sizes[18], nEr = in_sizes[20], nEc = in_sizes[22];

    // ---- workspace layout (~161 MB) ----
    size_t NB = (size_t)(NP > NA ? NP : NA) * NFEAT;
    float* Z1 = (float*)d_ws;       // P1 (lives to the end)
    float* Z2 = Z1 + NB;            // T / Au1 / P2
    float* Z3 = Z2 + NB;            // T / P1t / h
    float* s0   = Z3 + NB;          // NP
    float* s1   = s0 + NP;          // NP
    float* Wc0  = s1 + NP;          // 256*256: W0rp+W0w+W0c
    float* Wc1  = Wc0 + NFEAT * NFEAT;
    // int region (CSR)
    int* ib   = (int*)(Wc1 + NFEAT * NFEAT);
    int* degW = ib;                 // NP
    int* degR = degW + NP;          // NA
    int* degC = degR + NA;          // NP
    int* curW = degC + NP;          // NP
    int* curR = curW + NP;          // NA
    int* curC = curR + NA;          // NP
    int* offW = curC + NP;          // NP+1
    int* offR = offW + NP + 1;      // NA+1
    int* offC = offR + NA + 1;      // NP+1
    int* listW = offC + NP + 1;     // nEw
    int* listR = listW + nEw;       // nEr
    int* listC = listR + nEr;       // nEc

    float* out   = (float*)d_out;                 // logits [NP, NC]
    float* alpha = out + (size_t)NP * NC;         // [2, NP]

    // ---- build CSR for the 3 relations ----
    hipMemsetAsync(degW, 0, (size_t)2 * (NP + NA + NP) * sizeof(int), stream); // deg + cur

    deg_int_kernel<<<(nEw + 255) / 256, 256, 0, stream>>>(w_dst, degW, nEw);
    deg_int_kernel<<<(nEr + 255) / 256, 256, 0, stream>>>(r_dst, degR, nEr);
    deg_int_kernel<<<(nEc + 255) / 256, 256, 0, stream>>>(c_dst, degC, nEc);

    scan3_kernel<<<3, 256, 0, stream>>>(degW, NP, offW, degR, NA, offR, degC, NP, offC);

    fill_csr_kernel<<<(nEw + 255) / 256, 256, 0, stream>>>(w_src, w_dst, nEw, offW, curW, listW);
    fill_csr_kernel<<<(nEr + 255) / 256, 256, 0, stream>>>(r_src, r_dst, nEr, offR, curR, listR);
    fill_csr_kernel<<<(nEc + 255) / 256, 256, 0, stream>>>(c_src, c_dst, nEc, offC, curC, listC);

    int nW = NFEAT * NFEAT;
    addw3_kernel<<<(nW + 255) / 256, 256, 0, stream>>>(W0rp, W0w, W0c, Wc0, nW);
    addw3_kernel<<<(nW + 255) / 256, 256, 0, stream>>>(W1rp, W1w, W1c, Wc1, nW);

    dim3 blk(256);
    dim3 gP((NP + BM - 1) / BM, NFEAT / BN);
    dim3 gA((NA + BM - 1) / BM, NFEAT / BN);
    dim3 gR((NP + BM - 1) / BM);
    int nodeP = (NP + 3) / 4, nodeA = (NA + 3) / 4;

    // --- L0 paper: P1 = relu(Xp@W0rp + b + mean_w(Xa@W0w) + mean_c(Xp@W0c)) ---
    gemm_k<<<gP, blk, 0, stream>>>(x_paper, W0rp, b0rp, 0, Z1, NP, NFEAT);
    gemm_k<<<gA, blk, 0, stream>>>(emb_author, W0w, nullptr, 0, Z2, NA, NFEAT);
    agg_csr_kernel<<<nodeP, blk, 0, stream>>>(Z2, offW, listW, Z1, 0, NP);
    gemm_k<<<gP, blk, 0, stream>>>(x_paper, W0c, nullptr, 0, Z2, NP, NFEAT);
    agg_csr_kernel<<<nodeP, blk, 0, stream>>>(Z2, offC, listC, Z1, 1, NP);   // + relu => P1

    // --- L0 author: Au1 = relu(Xa@W0ra + b + mean_rev(Xp@W0rev)) ---
    gemm_k<<<gA, blk, 0, stream>>>(emb_author, W0ra, b0ra, 0, Z2, NA, NFEAT);
    gemm_k<<<gP, blk, 0, stream>>>(x_paper, W0rev, nullptr, 0, Z3, NP, NFEAT);
    agg_csr_kernel<<<nodeA, blk, 0, stream>>>(Z3, offR, listR, Z2, 1, NA);   // + relu => Au1

    // --- L1 paper: P2 = relu(P1@W1rp + b + mean_w(Au1@W1w) + mean_c(P1@W1c)) ---
    gemm_k<<<gA, blk, 0, stream>>>(Z2, W1w, nullptr, 0, Z3, NA, NFEAT);      // T = Au1@W1w
    gemm_k<<<gP, blk, 0, stream>>>(Z1, W1rp, b1rp, 0, Z2, NP, NFEAT);        // P2pre (Au1 dead)
    agg_csr_kernel<<<nodeP, blk, 0, stream>>>(Z3, offW, listW, Z2, 0, NP);
    gemm_k<<<gP, blk, 0, stream>>>(Z1, W1c, nullptr, 0, Z3, NP, NFEAT);      // T = P1@W1c
    agg_csr_kernel<<<nodeP, blk, 0, stream>>>(Z3, offC, listC, Z2, 1, NP);   // + relu => P2

    // --- twin path: P1t in Z3; P2t fused into rowdot ---
    gemm_k<<<gP, blk, 0, stream>>>(x_paper, Wc0, b0rp, 1, Z3, NP, NFEAT);    // P1t
    rowdot_kernel<<<nodeP, blk, 0, stream>>>(Z1, Z3, s0, NP);                // s0 = P1·P1t
    gemm_rowdot_kernel<<<gR, blk, 0, stream>>>(Z3, Wc1, b1rp, Z2, s1, NP);   // s1 = P2·relu(P1t@Wc1+b)

    // --- summarize + head ---
    combine_kernel<<<nodeP, blk, 0, stream>>>(Z1, Z2, s0, s1, Z3, alpha, NP); // h in Z3
    dim3 gO((NP + BM - 1) / BM, NC / BN);
    gemm_k<<<gO, blk, 0, stream>>>(Z3, outW, outb, 0, out, NP, NC);
}

// Round 7
// 1089.550 us; speedup vs baseline: 7.1816x; 1.6225x over previous
//
#include <hip/hip_runtime.h>
#include <hip/hip_bf16.h>

#define NFEAT 256
#define BM 64
#define BN 64
#define BK 16

typedef __attribute__((ext_vector_type(8))) short bf16x8;   // MFMA A/B frag (4 VGPRs)
typedef __attribute__((ext_vector_type(4))) float f32x4;    // MFMA C/D frag
typedef __attribute__((ext_vector_type(8))) unsigned short us8;

__device__ __forceinline__ void f2hilo(float x, unsigned short& h, unsigned short& l) {
    __hip_bfloat16 hb = __float2bfloat16(x);          // RNE
    float hf = __bfloat162float(hb);
    __hip_bfloat16 lb = __float2bfloat16(x - hf);
    h = *reinterpret_cast<unsigned short*>(&hb);
    l = *reinterpret_cast<unsigned short*>(&lb);
}

// o = a + b + c (elementwise), n elements (folded twin weights, fp32)
__global__ __launch_bounds__(256) void addw3_kernel(const float* __restrict__ a,
                                                    const float* __restrict__ b,
                                                    const float* __restrict__ c,
                                                    float* __restrict__ o, int n) {
    int i = blockIdx.x * 256 + threadIdx.x;
    if (i < n) o[i] = a[i] + b[i] + c[i];
}

// W fp32 [K][N] -> transposed split-bf16 planes Th/Tl [N][K]
__global__ __launch_bounds__(256) void cvtW_kernel(const float* __restrict__ W, int K, int N,
                                                   unsigned short* __restrict__ Th,
                                                   unsigned short* __restrict__ Tl) {
    int idx = blockIdx.x * 256 + threadIdx.x;
    if (idx >= K * N) return;
    int k = idx / N, c = idx - k * N;
    unsigned short h, l;
    f2hilo(W[idx], h, l);
    Th[(size_t)c * K + k] = h;
    Tl[(size_t)c * K + k] = l;
}

__global__ __launch_bounds__(256) void deg_int_kernel(const int* __restrict__ dst,
                                                      int* __restrict__ deg, int nE) {
    int e = blockIdx.x * 256 + threadIdx.x;
    if (e < nE) atomicAdd(&deg[dst[e]], 1);
}

// ---- parallel scan: phase1 per-256-block inclusive scan + block sums ----
__global__ __launch_bounds__(256) void scan_p1(const int* __restrict__ deg, int n,
                                               int* __restrict__ off, int* __restrict__ bsum) {
    __shared__ int tmp[256];
    int tid = threadIdx.x;
    int i = blockIdx.x * 256 + tid;
    tmp[tid] = (i < n) ? deg[i] : 0;
    __syncthreads();
    #pragma unroll
    for (int ofs = 1; ofs < 256; ofs <<= 1) {
        int t = (tid >= ofs) ? tmp[tid - ofs] : 0;
        __syncthreads();
        tmp[tid] += t;
        __syncthreads();
    }
    if (i < n) off[i + 1] = tmp[tid];
    if (tid == 255) bsum[blockIdx.x] = tmp[255];
}

// phase2: inclusive scan of the (<=256) block sums; 3 relations, 1 block each
__global__ __launch_bounds__(256) void scan_p2(int* __restrict__ bA, int nA,
                                               int* __restrict__ bB, int nB,
                                               int* __restrict__ bC, int nC) {
    int* bs; int nb;
    if (blockIdx.x == 0) { bs = bA; nb = nA; }
    else if (blockIdx.x == 1) { bs = bB; nb = nB; }
    else { bs = bC; nb = nC; }
    __shared__ int tmp[256];
    int tid = threadIdx.x;
    tmp[tid] = (tid < nb) ? bs[tid] : 0;
    __syncthreads();
    #pragma unroll
    for (int ofs = 1; ofs < 256; ofs <<= 1) {
        int t = (tid >= ofs) ? tmp[tid - ofs] : 0;
        __syncthreads();
        tmp[tid] += t;
        __syncthreads();
    }
    if (tid < nb) bs[tid] = tmp[tid];
}

// phase3: add prior-block totals; set off[0]=0
__global__ __launch_bounds__(256) void scan_p3(int n, int* __restrict__ off,
                                               const int* __restrict__ bsum) {
    int i = blockIdx.x * 256 + threadIdx.x;
    if (i == 0) off[0] = 0;
    if (i >= n) return;
    int b = blockIdx.x;
    if (b > 0) off[i + 1] += bsum[b - 1];
}

// list[off[dst]+pos] = src  (pos via per-dst cursor)
__global__ __launch_bounds__(256) void fill_csr_kernel(const int* __restrict__ src,
                                                       const int* __restrict__ dst, int nE,
                                                       const int* __restrict__ off,
                                                       int* __restrict__ cursor,
                                                       int* __restrict__ list) {
    int e = blockIdx.x * 256 + threadIdx.x;
    if (e >= nE) return;
    int d = dst[e];
    int pos = atomicAdd(&cursor[d], 1);
    list[off[d] + pos] = src[e];
}

// per dst row r: D[r,:] += mean over incoming edges of T[src,:]; optional fused relu.
__global__ __launch_bounds__(256) void agg_csr_kernel(const float* __restrict__ T,
                                                      const int* __restrict__ off,
                                                      const int* __restrict__ list,
                                                      float* __restrict__ D,
                                                      int do_relu, int M) {
    int r = blockIdx.x * 4 + (threadIdx.x >> 6);
    if (r >= M) return;
    int lane = threadIdx.x & 63;
    int start = off[r], end = off[r + 1];
    float4 acc = make_float4(0.f, 0.f, 0.f, 0.f);
    for (int e = start; e < end; ++e) {
        int s = list[e];
        float4 v = ((const float4*)(T + (size_t)s * NFEAT))[lane];
        acc.x += v.x; acc.y += v.y; acc.z += v.z; acc.w += v.w;
    }
    int cnt = end - start;
    float inv = (cnt > 0) ? 1.0f / (float)cnt : 0.0f;
    float4 d = ((float4*)(D + (size_t)r * NFEAT))[lane];
    d.x += acc.x * inv; d.y += acc.y * inv;
    d.z += acc.z * inv; d.w += acc.w * inv;
    if (do_relu) {
        d.x = fmaxf(d.x, 0.f); d.y = fmaxf(d.y, 0.f);
        d.z = fmaxf(d.z, 0.f); d.w = fmaxf(d.w, 0.f);
    }
    ((float4*)(D + (size_t)r * NFEAT))[lane] = d;
}

// s[n] = dot(A[n,:], B[n,:]) over 256 feats
__global__ __launch_bounds__(256) void rowdot_kernel(const float* __restrict__ A,
                                                     const float* __restrict__ B,
                                                     float* __restrict__ s, int M) {
    int n = blockIdx.x * 4 + (threadIdx.x >> 6);
    if (n >= M) return;
    int lane = threadIdx.x & 63;
    float4 a = ((const float4*)(A + (size_t)n * NFEAT))[lane];
    float4 b = ((const float4*)(B + (size_t)n * NFEAT))[lane];
    float d = a.x * b.x + a.y * b.y + a.z * b.z + a.w * b.w;
    #pragma unroll
    for (int off = 32; off > 0; off >>= 1) d += __shfl_down(d, off);
    if (lane == 0) s[n] = d;
}

// per node: softmax(s0,s1) -> alpha; h = a0*P1 + a1*P2 (all fp32)
__global__ __launch_bounds__(256) void combine_kernel(const float* __restrict__ P1,
                                                      const float* __restrict__ P2,
                                                      const float* __restrict__ s0,
                                                      const float* __restrict__ s1,
                                                      float* __restrict__ h,
                                                      float* __restrict__ alpha,
                                                      int M) {
    int n = blockIdx.x * 4 + (threadIdx.x >> 6);
    if (n >= M) return;
    int lane = threadIdx.x & 63;
    float v0 = s0[n], v1 = s1[n];
    float m = fmaxf(v0, v1);
    float e0 = expf(v0 - m), e1 = expf(v1 - m);
    float inv = 1.0f / (e0 + e1);
    float a0 = e0 * inv, a1 = e1 * inv;
    float4 p1 = ((const float4*)(P1 + (size_t)n * NFEAT))[lane];
    float4 p2 = ((const float4*)(P2 + (size_t)n * NFEAT))[lane];
    float4 hv;
    hv.x = a0 * p1.x + a1 * p2.x;
    hv.y = a0 * p1.y + a1 * p2.y;
    hv.z = a0 * p1.z + a1 * p2.z;
    hv.w = a0 * p1.w + a1 * p2.w;
    ((float4*)(h + (size_t)n * NFEAT))[lane] = hv;
    if (lane == 0) {
        alpha[n]     = a0;
        alpha[M + n] = a1;
    }
}

// C[M,N] = maybe_relu(X[M,256] @ W[256,N] + maybe_bias)
// X fp32 (split to bf16 hi/lo in staging); W pre-split bf16 [N][K] planes.
// 3-segment split-precision: Xh@Wh + Xl@Wh + Xh@Wl (error ~2^-17 rel).
// 128x128 tile, 4 waves (2x2), each wave 64x64 via 4x4 16x16x32 MFMA frags.
__global__ __launch_bounds__(256, 2) void gemm_mfma(
    const float* __restrict__ X,
    const unsigned short* __restrict__ Wh,
    const unsigned short* __restrict__ Wl,
    const float* __restrict__ bias, int do_relu,
    float* __restrict__ C, int M, int N)
{
    __shared__ unsigned short Ah[128][40];  // pad to 40 (80B rows, 16B-aligned)
    __shared__ unsigned short Al[128][40];
    __shared__ unsigned short Bh[128][40];
    __shared__ unsigned short Bl[128][40];

    int tid = threadIdx.x;
    int lane = tid & 63;
    int w = tid >> 6;
    int wr = w >> 1, wc = w & 1;
    int row0 = blockIdx.x * 128, col0 = blockIdx.y * 128;

    int sr = tid >> 1;             // staging row (A) / col (B), 0..127
    int sk = (tid & 1) * 16;       // staging k offset {0,16}

    int grow = row0 + sr; if (grow >= M) grow = M - 1;
    const float* Xrow = X + (size_t)grow * NFEAT;
    const unsigned short* Whrow = Wh + (size_t)(col0 + sr) * NFEAT;
    const unsigned short* Wlrow = Wl + (size_t)(col0 + sr) * NFEAT;

    f32x4 acc[4][4];
    #pragma unroll
    for (int m = 0; m < 4; ++m)
        #pragma unroll
        for (int n = 0; n < 4; ++n)
            acc[m][n] = (f32x4)(0.f);

    int fr = lane & 15;   // frag row/col
    int fg = lane >> 4;   // frag k-group

    for (int k0 = 0; k0 < NFEAT; k0 += 32) {
        // load + convert A (fp32 -> hi/lo bf16)
        unsigned short hh[16], ll[16];
        #pragma unroll
        for (int q = 0; q < 4; ++q) {
            float4 v = *(const float4*)(Xrow + k0 + sk + q * 4);
            f2hilo(v.x, hh[q*4+0], ll[q*4+0]);
            f2hilo(v.y, hh[q*4+1], ll[q*4+1]);
            f2hilo(v.z, hh[q*4+2], ll[q*4+2]);
            f2hilo(v.w, hh[q*4+3], ll[q*4+3]);
        }
        // load B (already bf16 hi/lo, [N][K])
        us8 bh0 = *(const us8*)(Whrow + k0 + sk);
        us8 bh1 = *(const us8*)(Whrow + k0 + sk + 8);
        us8 bl0 = *(const us8*)(Wlrow + k0 + sk);
        us8 bl1 = *(const us8*)(Wlrow + k0 + sk + 8);
        __syncthreads();
        *(us8*)&Ah[sr][sk]     = *(us8*)&hh[0];
        *(us8*)&Ah[sr][sk + 8] = *(us8*)&hh[8];
        *(us8*)&Al[sr][sk]     = *(us8*)&ll[0];
        *(us8*)&Al[sr][sk + 8] = *(us8*)&ll[8];
        *(us8*)&Bh[sr][sk]     = bh0;
        *(us8*)&Bh[sr][sk + 8] = bh1;
        *(us8*)&Bl[sr][sk]     = bl0;
        *(us8*)&Bl[sr][sk + 8] = bl1;
        __syncthreads();

        bf16x8 ah[4], al[4], bhf[4], blf[4];
        #pragma unroll
        for (int m = 0; m < 4; ++m) {
            int r = wr * 64 + m * 16 + fr;
            ah[m] = *(const bf16x8*)&Ah[r][fg * 8];
            al[m] = *(const bf16x8*)&Al[r][fg * 8];
        }
        #pragma unroll
        for (int n = 0; n < 4; ++n) {
            int c = wc * 64 + n * 16 + fr;
            bhf[n] = *(const bf16x8*)&Bh[c][fg * 8];
            blf[n] = *(const bf16x8*)&Bl[c][fg * 8];
        }
        #pragma unroll
        for (int m = 0; m < 4; ++m)
            #pragma unroll
            for (int n = 0; n < 4; ++n) {
                acc[m][n] = __builtin_amdgcn_mfma_f32_16x16x32_bf16(ah[m], bhf[n], acc[m][n], 0, 0, 0);
                acc[m][n] = __builtin_amdgcn_mfma_f32_16x16x32_bf16(al[m], bhf[n], acc[m][n], 0, 0, 0);
                acc[m][n] = __builtin_amdgcn_mfma_f32_16x16x32_bf16(ah[m], blf[n], acc[m][n], 0, 0, 0);
            }
    }

    // epilogue: C/D layout col=lane&15, row=(lane>>4)*4+i
    #pragma unroll
    for (int n = 0; n < 4; ++n) {
        int c = col0 + wc * 64 + n * 16 + fr;
        float bv = bias ? bias[c] : 0.f;
        #pragma unroll
        for (int m = 0; m < 4; ++m) {
            int rbase = row0 + wr * 64 + m * 16 + fg * 4;
            #pragma unroll
            for (int i = 0; i < 4; ++i) {
                int r = rbase + i;
                if (r < M) {
                    float v = acc[m][n][i] + bv;
                    if (do_relu) v = fmaxf(v, 0.f);
                    C[(size_t)r * N + c] = v;
                }
            }
        }
    }
}

// s[r] = dot( relu(X[r,:]@W + bias), P[r,:] ), all fp32 (twin L1 fused)
__global__ __launch_bounds__(256) void gemm_rowdot_kernel(
    const float* __restrict__ X, const float* __restrict__ W,
    const float* __restrict__ bias, const float* __restrict__ P,
    float* __restrict__ s, int M)
{
    __shared__ float Xs[BK][BM];
    __shared__ float Ws[BK][BN];
    __shared__ float srow[BM];

    int tid = threadIdx.x;
    int row0 = blockIdx.x * BM;

    int lr = tid & 63;
    int lk = (tid >> 6) * 4;
    int wk = tid >> 4;
    int wc = (tid & 15) * 4;
    int ty = tid >> 4;
    int tx = tid & 15;

    int grow = row0 + lr;
    if (grow >= M) grow = M - 1;

    if (tid < BM) srow[tid] = 0.f;

    float rp[4] = {0.f, 0.f, 0.f, 0.f};

    for (int col0 = 0; col0 < NFEAT; col0 += BN) {
        float acc[4][4] = {{0.f}};
        for (int k0 = 0; k0 < NFEAT; k0 += BK) {
            float4 xv = *(const float4*)(X + (size_t)grow * NFEAT + k0 + lk);
            float4 wv = *(const float4*)(W + (size_t)(k0 + wk) * NFEAT + col0 + wc);
            __syncthreads();
            Xs[lk + 0][lr] = xv.x;
            Xs[lk + 1][lr] = xv.y;
            Xs[lk + 2][lr] = xv.z;
            Xs[lk + 3][lr] = xv.w;
            *(float4*)&Ws[wk][wc] = wv;
            __syncthreads();
            #pragma unroll
            for (int kk = 0; kk < BK; ++kk) {
                float4 a = *(const float4*)&Xs[kk][ty * 4];
                float4 b = *(const float4*)&Ws[kk][tx * 4];
                acc[0][0] += a.x * b.x; acc[0][1] += a.x * b.y;
                acc[0][2] += a.x * b.z; acc[0][3] += a.x * b.w;
                acc[1][0] += a.y * b.x; acc[1][1] += a.y * b.y;
                acc[1][2] += a.y * b.z; acc[1][3] += a.y * b.w;
                acc[2][0] += a.z * b.x; acc[2][1] += a.z * b.y;
                acc[2][2] += a.z * b.z; acc[2][3] += a.z * b.w;
                acc[3][0] += a.w * b.x; acc[3][1] += a.w * b.y;
                acc[3][2] += a.w * b.z; acc[3][3] += a.w * b.w;
            }
        }
        int c0 = col0 + tx * 4;
        #pragma unroll
        for (int i = 0; i < 4; ++i) {
            int r = row0 + ty * 4 + i;
            if (r >= M) continue;
            float4 p = *(const float4*)(P + (size_t)r * NFEAT + c0);
            float v0 = fmaxf(acc[i][0] + bias[c0 + 0], 0.f);
            float v1 = fmaxf(acc[i][1] + bias[c0 + 1], 0.f);
            float v2 = fmaxf(acc[i][2] + bias[c0 + 2], 0.f);
            float v3 = fmaxf(acc[i][3] + bias[c0 + 3], 0.f);
            rp[i] += v0 * p.x + v1 * p.y + v2 * p.z + v3 * p.w;
        }
    }
    __syncthreads();
    #pragma unroll
    for (int i = 0; i < 4; ++i) atomicAdd(&srow[ty * 4 + i], rp[i]);
    __syncthreads();
    if (tid < BM && row0 + tid < M) s[row0 + tid] = srow[tid];
}

extern "C" void kernel_launch(void* const* d_in, const int* in_sizes, int n_in,
                              void* d_out, int out_size, void* d_ws, size_t ws_size,
                              hipStream_t stream)
{
    const float* x_paper    = (const float*)d_in[0];
    const float* emb_author = (const float*)d_in[1];
    const float* W0rp = (const float*)d_in[2];
    const float* b0rp = (const float*)d_in[3];
    const float* W0ra = (const float*)d_in[4];
    const float* b0ra = (const float*)d_in[5];
    const float* W0w  = (const float*)d_in[6];
    const float* W0rev= (const float*)d_in[7];
    const float* W0c  = (const float*)d_in[8];
    const float* W1rp = (const float*)d_in[9];
    const float* b1rp = (const float*)d_in[10];
    const float* W1w  = (const float*)d_in[13];
    const float* W1c  = (const float*)d_in[15];
    const float* outW = (const float*)d_in[16];
    const float* outb = (const float*)d_in[17];
    const int* w_src = (const int*)d_in[18];
    const int* w_dst = (const int*)d_in[19];
    const int* r_src = (const int*)d_in[20];
    const int* r_dst = (const int*)d_in[21];
    const int* c_src = (const int*)d_in[22];
    const int* c_dst = (const int*)d_in[23];

    const int NP = in_sizes[0] / NFEAT;   // 50000
    const int NA = in_sizes[1] / NFEAT;   // 50000
    const int NC = in_sizes[17];          // 128
    const int nEw = in_sizes[18], nEr = in_sizes[20], nEc = in_sizes[22];

    // ---- workspace layout (~162 MB, known-safe scale) ----
    size_t NB = (size_t)(NP > NA ? NP : NA) * NFEAT;
    float* Z1 = (float*)d_ws;       // P1
    float* Z2 = Z1 + NB;            // T / Au1 / P2
    float* Z3 = Z2 + NB;            // T / P1t / h
    float* s0   = Z3 + NB;          // NP
    float* s1   = s0 + NP;          // NP
    float* Wc0f = s1 + NP;          // 256*256 fp32 folded
    float* Wc1f = Wc0f + NFEAT * NFEAT;
    // split-bf16 transposed weights: 11 slots x (hi 65536 + lo 65536) ushorts
    unsigned short* Wt = (unsigned short*)(Wc1f + NFEAT * NFEAT);
    const size_t WSLOT = 2 * 65536;
    #define WT_HI(i) (Wt + (size_t)(i) * WSLOT)
    #define WT_LO(i) (Wt + (size_t)(i) * WSLOT + 65536)
    // int region (CSR)
    int* ib   = (int*)(Wt + 11 * WSLOT);
    int* degW = ib;                 // NP
    int* degR = degW + NP;          // NA
    int* degC = degR + NA;          // NP
    int* curW = degC + NP;          // NP
    int* curR = curW + NP;          // NA
    int* curC = curR + NA;          // NP
    int* offW = curC + NP;          // NP+1
    int* offR = offW + NP + 1;      // NA+1
    int* offC = offR + NA + 1;      // NP+1
    int* bsW  = offC + NP + 1;      // 256
    int* bsR  = bsW + 256;          // 256
    int* bsC  = bsR + 256;          // 256
    int* listW = bsC + 256;         // nEw
    int* listR = listW + nEw;       // nEr
    int* listC = listR + nEr;       // nEc

    float* out   = (float*)d_out;                 // logits [NP, NC]
    float* alpha = out + (size_t)NP * NC;         // [2, NP]

    // ---- build CSR ----
    hipMemsetAsync(degW, 0, (size_t)2 * (NP + NA + NP) * sizeof(int), stream);

    deg_int_kernel<<<(nEw + 255) / 256, 256, 0, stream>>>(w_dst, degW, nEw);
    deg_int_kernel<<<(nEr + 255) / 256, 256, 0, stream>>>(r_dst, degR, nEr);
    deg_int_kernel<<<(nEc + 255) / 256, 256, 0, stream>>>(c_dst, degC, nEc);

    int nbP = (NP + 255) / 256, nbA = (NA + 255) / 256;
    scan_p1<<<nbP, 256, 0, stream>>>(degW, NP, offW, bsW);
    scan_p1<<<nbA, 256, 0, stream>>>(degR, NA, offR, bsR);
    scan_p1<<<nbP, 256, 0, stream>>>(degC, NP, offC, bsC);
    scan_p2<<<3, 256, 0, stream>>>(bsW, nbP, bsR, nbA, bsC, nbP);
    scan_p3<<<nbP, 256, 0, stream>>>(NP, offW, bsW);
    scan_p3<<<nbA, 256, 0, stream>>>(NA, offR, bsR);
    scan_p3<<<nbP, 256, 0, stream>>>(NP, offC, bsC);

    fill_csr_kernel<<<(nEw + 255) / 256, 256, 0, stream>>>(w_src, w_dst, nEw, offW, curW, listW);
    fill_csr_kernel<<<(nEr + 255) / 256, 256, 0, stream>>>(r_src, r_dst, nEr, offR, curR, listR);
    fill_csr_kernel<<<(nEc + 255) / 256, 256, 0, stream>>>(c_src, c_dst, nEc, offC, curC, listC);

    // ---- fold twin weights + convert all weights to transposed split-bf16 ----
    int nW = NFEAT * NFEAT;
    int wblk = (nW + 255) / 256;
    addw3_kernel<<<wblk, 256, 0, stream>>>(W0rp, W0w, W0c, Wc0f, nW);
    addw3_kernel<<<wblk, 256, 0, stream>>>(W1rp, W1w, W1c, Wc1f, nW);

    cvtW_kernel<<<wblk, 256, 0, stream>>>(W0rp, NFEAT, NFEAT, WT_HI(0), WT_LO(0));
    cvtW_kernel<<<wblk, 256, 0, stream>>>(W0w,  NFEAT, NFEAT, WT_HI(1), WT_LO(1));
    cvtW_kernel<<<wblk, 256, 0, stream>>>(W0c,  NFEAT, NFEAT, WT_HI(2), WT_LO(2));
    cvtW_kernel<<<wblk, 256, 0, stream>>>(W0ra, NFEAT, NFEAT, WT_HI(3), WT_LO(3));
    cvtW_kernel<<<wblk, 256, 0, stream>>>(W0rev,NFEAT, NFEAT, WT_HI(4), WT_LO(4));
    cvtW_kernel<<<wblk, 256, 0, stream>>>(W1w,  NFEAT, NFEAT, WT_HI(5), WT_LO(5));
    cvtW_kernel<<<wblk, 256, 0, stream>>>(W1rp, NFEAT, NFEAT, WT_HI(6), WT_LO(6));
    cvtW_kernel<<<wblk, 256, 0, stream>>>(W1c,  NFEAT, NFEAT, WT_HI(7), WT_LO(7));
    cvtW_kernel<<<wblk, 256, 0, stream>>>(Wc0f, NFEAT, NFEAT, WT_HI(8), WT_LO(8));
    cvtW_kernel<<<(NFEAT * NC + 255) / 256, 256, 0, stream>>>(outW, NFEAT, NC, WT_HI(9), WT_LO(9));

    dim3 blk(256);
    dim3 gM((NP + 127) / 128, NFEAT / 128);   // MFMA GEMM grid, N=256
    dim3 gMA((NA + 127) / 128, NFEAT / 128);
    dim3 gMO((NP + 127) / 128, NC / 128);     // head, N=128
    dim3 gR((NP + BM - 1) / BM);
    int nodeP = (NP + 3) / 4, nodeA = (NA + 3) / 4;

    // --- L0 paper: P1 = relu(Xp@W0rp + b + mean_w(Xa@W0w) + mean_c(Xp@W0c)) ---
    gemm_mfma<<<gM, blk, 0, stream>>>(x_paper, WT_HI(0), WT_LO(0), b0rp, 0, Z1, NP, NFEAT);
    gemm_mfma<<<gMA, blk, 0, stream>>>(emb_author, WT_HI(1), WT_LO(1), nullptr, 0, Z2, NA, NFEAT);
    agg_csr_kernel<<<nodeP, blk, 0, stream>>>(Z2, offW, listW, Z1, 0, NP);
    gemm_mfma<<<gM, blk, 0, stream>>>(x_paper, WT_HI(2), WT_LO(2), nullptr, 0, Z2, NP, NFEAT);
    agg_csr_kernel<<<nodeP, blk, 0, stream>>>(Z2, offC, listC, Z1, 1, NP);   // + relu => P1

    // --- L0 author: Au1 = relu(Xa@W0ra + b + mean_rev(Xp@W0rev)) ---
    gemm_mfma<<<gMA, blk, 0, stream>>>(emb_author, WT_HI(3), WT_LO(3), b0ra, 0, Z2, NA, NFEAT);
    gemm_mfma<<<gM, blk, 0, stream>>>(x_paper, WT_HI(4), WT_LO(4), nullptr, 0, Z3, NP, NFEAT);
    agg_csr_kernel<<<nodeA, blk, 0, stream>>>(Z3, offR, listR, Z2, 1, NA);   // + relu => Au1

    // --- L1 paper: P2 = relu(P1@W1rp + b + mean_w(Au1@W1w) + mean_c(P1@W1c)) ---
    gemm_mfma<<<gMA, blk, 0, stream>>>(Z2, WT_HI(5), WT_LO(5), nullptr, 0, Z3, NA, NFEAT); // T = Au1@W1w
    gemm_mfma<<<gM, blk, 0, stream>>>(Z1, WT_HI(6), WT_LO(6), b1rp, 0, Z2, NP, NFEAT);     // P2pre
    agg_csr_kernel<<<nodeP, blk, 0, stream>>>(Z3, offW, listW, Z2, 0, NP);
    gemm_mfma<<<gM, blk, 0, stream>>>(Z1, WT_HI(7), WT_LO(7), nullptr, 0, Z3, NP, NFEAT);  // T = P1@W1c
    agg_csr_kernel<<<nodeP, blk, 0, stream>>>(Z3, offC, listC, Z2, 1, NP);   // + relu => P2

    // --- twin path: P1t in Z3; P2t fused into rowdot (fp32) ---
    gemm_mfma<<<gM, blk, 0, stream>>>(x_paper, WT_HI(8), WT_LO(8), b0rp, 1, Z3, NP, NFEAT); // P1t
    rowdot_kernel<<<nodeP, blk, 0, stream>>>(Z1, Z3, s0, NP);                 // s0 = P1·P1t
    gemm_rowdot_kernel<<<gR, blk, 0, stream>>>(Z3, Wc1f, b1rp, Z2, s1, NP);   // s1 = P2·relu(P1t@Wc1+b)

    // --- summarize + head ---
    combine_kernel<<<nodeP, blk, 0, stream>>>(Z1, Z2, s0, s1, Z3, alpha, NP); // h in Z3
    gemm_mfma<<<gMO, blk, 0, stream>>>(Z3, WT_HI(9), WT_LO(9), outb, 0, out, NP, NC);
}

// Round 8
// 879.328 us; speedup vs baseline: 8.8985x; 1.2391x over previous
//
#include <hip/hip_runtime.h>
#include <hip/hip_bf16.h>

#define NFEAT 256

typedef __attribute__((ext_vector_type(8))) short bf16x8;   // MFMA A/B frag (4 VGPRs)
typedef __attribute__((ext_vector_type(4))) float f32x4;    // MFMA C/D frag
typedef __attribute__((ext_vector_type(8))) unsigned short us8;

__device__ __forceinline__ float bf2f(unsigned short u) {
    union { unsigned int i; float f; } v; v.i = ((unsigned int)u) << 16; return v.f;
}

__device__ __forceinline__ void f2hilo(float x, unsigned short& h, unsigned short& l) {
    __hip_bfloat16 hb = __float2bfloat16(x);          // RNE
    float hf = __bfloat162float(hb);
    __hip_bfloat16 lb = __float2bfloat16(x - hf);
    h = *reinterpret_cast<unsigned short*>(&hb);
    l = *reinterpret_cast<unsigned short*>(&lb);
}

// ---------------- weight conversion ----------------
// 8 square fp32 weights [256][256] -> transposed split-bf16 planes (slots 0..7)
__global__ __launch_bounds__(256) void cvt8_kernel(
    const float* w0, const float* w1, const float* w2, const float* w3,
    const float* w4, const float* w5, const float* w6, const float* w7,
    unsigned short* base)
{
    int wi = blockIdx.y;
    const float* W = (wi==0)?w0:(wi==1)?w1:(wi==2)?w2:(wi==3)?w3:
                     (wi==4)?w4:(wi==5)?w5:(wi==6)?w6:w7;
    int idx = blockIdx.x * 256 + threadIdx.x;     // 0..65535
    int k = idx >> 8, c = idx & 255;
    unsigned short h, l;
    f2hilo(W[idx], h, l);
    unsigned short* Th = base + (size_t)wi * 131072;
    Th[c * 256 + k] = h;
    Th[65536 + c * 256 + k] = l;
}

// folded twin weights: slot8 = a0+a1+a2 ; slot9 = b0+b1+b2
__global__ __launch_bounds__(256) void cvtfold_kernel(
    const float* a0, const float* a1, const float* a2,
    const float* b0, const float* b1, const float* b2,
    unsigned short* base)
{
    int wi = blockIdx.y;
    int idx = blockIdx.x * 256 + threadIdx.x;
    float v = wi ? (b0[idx] + b1[idx] + b2[idx]) : (a0[idx] + a1[idx] + a2[idx]);
    int k = idx >> 8, c = idx & 255;
    unsigned short h, l;
    f2hilo(v, h, l);
    unsigned short* Th = base + (size_t)(8 + wi) * 131072;
    Th[c * 256 + k] = h;
    Th[65536 + c * 256 + k] = l;
}

// outW fp32 [256][128] -> slot 10
__global__ __launch_bounds__(256) void cvtrect_kernel(const float* W, unsigned short* base) {
    int idx = blockIdx.x * 256 + threadIdx.x;     // 0..32767
    if (idx >= 256 * 128) return;
    int k = idx >> 7, c = idx & 127;
    unsigned short h, l;
    f2hilo(W[idx], h, l);
    unsigned short* Th = base + (size_t)10 * 131072;
    Th[c * 256 + k] = h;
    Th[65536 + c * 256 + k] = l;
}

// ---------------- CSR build ----------------
__global__ __launch_bounds__(256) void deg_int_kernel(const int* __restrict__ dst,
                                                      int* __restrict__ deg, int nE) {
    int e = blockIdx.x * 256 + threadIdx.x;
    if (e < nE) atomicAdd(&deg[dst[e]], 1);
}

__global__ __launch_bounds__(256) void scan_p1(const int* __restrict__ deg, int n,
                                               int* __restrict__ off, int* __restrict__ bsum) {
    __shared__ int tmp[256];
    int tid = threadIdx.x;
    int i = blockIdx.x * 256 + tid;
    tmp[tid] = (i < n) ? deg[i] : 0;
    __syncthreads();
    #pragma unroll
    for (int ofs = 1; ofs < 256; ofs <<= 1) {
        int t = (tid >= ofs) ? tmp[tid - ofs] : 0;
        __syncthreads();
        tmp[tid] += t;
        __syncthreads();
    }
    if (i < n) off[i + 1] = tmp[tid];
    if (tid == 255) bsum[blockIdx.x] = tmp[255];
}

__global__ __launch_bounds__(256) void scan_p2(int* __restrict__ bA, int nA,
                                               int* __restrict__ bB, int nB,
                                               int* __restrict__ bC, int nC) {
    int* bs; int nb;
    if (blockIdx.x == 0) { bs = bA; nb = nA; }
    else if (blockIdx.x == 1) { bs = bB; nb = nB; }
    else { bs = bC; nb = nC; }
    __shared__ int tmp[256];
    int tid = threadIdx.x;
    tmp[tid] = (tid < nb) ? bs[tid] : 0;
    __syncthreads();
    #pragma unroll
    for (int ofs = 1; ofs < 256; ofs <<= 1) {
        int t = (tid >= ofs) ? tmp[tid - ofs] : 0;
        __syncthreads();
        tmp[tid] += t;
        __syncthreads();
    }
    if (tid < nb) bs[tid] = tmp[tid];
}

__global__ __launch_bounds__(256) void scan_p3(int n, int* __restrict__ off,
                                               const int* __restrict__ bsum) {
    int i = blockIdx.x * 256 + threadIdx.x;
    if (i == 0) off[0] = 0;
    if (i >= n) return;
    int b = blockIdx.x;
    if (b > 0) off[i + 1] += bsum[b - 1];
}

__global__ __launch_bounds__(256) void fill_csr_kernel(const int* __restrict__ src,
                                                       const int* __restrict__ dst, int nE,
                                                       const int* __restrict__ off,
                                                       int* __restrict__ cursor,
                                                       int* __restrict__ list) {
    int e = blockIdx.x * 256 + threadIdx.x;
    if (e >= nE) return;
    int d = dst[e];
    int pos = atomicAdd(&cursor[d], 1);
    list[off[d] + pos] = src[e];
}

// ---------------- aggregation (gather, no atomics) ----------------
// mode_add=0: D[r] = mean; mode_add=1: D[r] += mean. Optional fused relu.
__global__ __launch_bounds__(256) void agg_csr_kernel(const float* __restrict__ T,
                                                      const int* __restrict__ off,
                                                      const int* __restrict__ list,
                                                      float* __restrict__ D,
                                                      int mode_add, int do_relu, int M) {
    int r = blockIdx.x * 4 + (threadIdx.x >> 6);
    if (r >= M) return;
    int lane = threadIdx.x & 63;
    int start = off[r], end = off[r + 1];
    float4 acc = make_float4(0.f, 0.f, 0.f, 0.f);
    for (int e = start; e < end; ++e) {
        int s = list[e];
        float4 v = ((const float4*)(T + (size_t)s * NFEAT))[lane];
        acc.x += v.x; acc.y += v.y; acc.z += v.z; acc.w += v.w;
    }
    int cnt = end - start;
    float inv = (cnt > 0) ? 1.0f / (float)cnt : 0.0f;
    float4 d;
    if (mode_add) {
        d = ((float4*)(D + (size_t)r * NFEAT))[lane];
        d.x += acc.x * inv; d.y += acc.y * inv;
        d.z += acc.z * inv; d.w += acc.w * inv;
    } else {
        d.x = acc.x * inv; d.y = acc.y * inv;
        d.z = acc.z * inv; d.w = acc.w * inv;
    }
    if (do_relu) {
        d.x = fmaxf(d.x, 0.f); d.y = fmaxf(d.y, 0.f);
        d.z = fmaxf(d.z, 0.f); d.w = fmaxf(d.w, 0.f);
    }
    ((float4*)(D + (size_t)r * NFEAT))[lane] = d;
}

// ---------------- alpha (softmax over 2 layer scores) ----------------
__global__ __launch_bounds__(256) void alpha_kernel(const float* __restrict__ s0,
                                                    const float* __restrict__ s1,
                                                    float* __restrict__ alpha, int M) {
    int n = blockIdx.x * 256 + threadIdx.x;
    if (n >= M) return;
    float v0 = s0[n], v1 = s1[n];
    float m = fmaxf(v0, v1);
    float e0 = expf(v0 - m), e1 = expf(v1 - m);
    float inv = 1.0f / (e0 + e1);
    alpha[n]     = e0 * inv;
    alpha[M + n] = e1 * inv;
}

// ---------------- multi-segment split-bf16 MFMA GEMM ----------------
// C[M,N] = maybe_relu( sum_s A_s[M,256] @ W_s[256,N] + bias )
// A fp32 (split to hi/lo in staging); W pre-split transposed planes [N][256].
// 128x128 tile, 4 waves (2x2), 3-segment split-precision per K-block.
struct Seg3 {
    const float *A0, *A1, *A2;
    const unsigned short *Wh0, *Wl0, *Wh1, *Wl1, *Wh2, *Wl2;
};

__global__ __launch_bounds__(256, 2) void gemm_ms(
    Seg3 sp, int nseg, const float* __restrict__ bias, int do_relu,
    float* __restrict__ C, int M, int N)
{
    __shared__ unsigned short Ah[128][40];
    __shared__ unsigned short Al[128][40];
    __shared__ unsigned short Bh[128][40];
    __shared__ unsigned short Bl[128][40];

    int tid = threadIdx.x;
    int lane = tid & 63;
    int w = tid >> 6;
    int wr = w >> 1, wc = w & 1;
    int row0 = blockIdx.x * 128, col0 = blockIdx.y * 128;
    int sr = tid >> 1;
    int sk = (tid & 1) * 16;
    int grow = row0 + sr; if (grow >= M) grow = M - 1;
    int fr = lane & 15;
    int fg = lane >> 4;

    f32x4 acc[4][4];
    #pragma unroll
    for (int m = 0; m < 4; ++m)
        #pragma unroll
        for (int n = 0; n < 4; ++n)
            acc[m][n] = (f32x4)(0.f);

    for (int s = 0; s < 3; ++s) {
        if (s >= nseg) break;
        const float* Xrow = ((s == 0) ? sp.A0 : (s == 1) ? sp.A1 : sp.A2) + (size_t)grow * NFEAT;
        const unsigned short* Whrow = ((s == 0) ? sp.Wh0 : (s == 1) ? sp.Wh1 : sp.Wh2) + (size_t)(col0 + sr) * NFEAT;
        const unsigned short* Wlrow = ((s == 0) ? sp.Wl0 : (s == 1) ? sp.Wl1 : sp.Wl2) + (size_t)(col0 + sr) * NFEAT;

        for (int k0 = 0; k0 < NFEAT; k0 += 32) {
            unsigned short hh[16], ll[16];
            #pragma unroll
            for (int q = 0; q < 4; ++q) {
                float4 v = *(const float4*)(Xrow + k0 + sk + q * 4);
                f2hilo(v.x, hh[q*4+0], ll[q*4+0]);
                f2hilo(v.y, hh[q*4+1], ll[q*4+1]);
                f2hilo(v.z, hh[q*4+2], ll[q*4+2]);
                f2hilo(v.w, hh[q*4+3], ll[q*4+3]);
            }
            us8 bh0 = *(const us8*)(Whrow + k0 + sk);
            us8 bh1 = *(const us8*)(Whrow + k0 + sk + 8);
            us8 bl0 = *(const us8*)(Wlrow + k0 + sk);
            us8 bl1 = *(const us8*)(Wlrow + k0 + sk + 8);
            __syncthreads();
            *(us8*)&Ah[sr][sk]     = *(us8*)&hh[0];
            *(us8*)&Ah[sr][sk + 8] = *(us8*)&hh[8];
            *(us8*)&Al[sr][sk]     = *(us8*)&ll[0];
            *(us8*)&Al[sr][sk + 8] = *(us8*)&ll[8];
            *(us8*)&Bh[sr][sk]     = bh0;
            *(us8*)&Bh[sr][sk + 8] = bh1;
            *(us8*)&Bl[sr][sk]     = bl0;
            *(us8*)&Bl[sr][sk + 8] = bl1;
            __syncthreads();

            bf16x8 ah[4], al[4], bhf[4], blf[4];
            #pragma unroll
            for (int m = 0; m < 4; ++m) {
                int r = wr * 64 + m * 16 + fr;
                ah[m] = *(const bf16x8*)&Ah[r][fg * 8];
                al[m] = *(const bf16x8*)&Al[r][fg * 8];
            }
            #pragma unroll
            for (int n = 0; n < 4; ++n) {
                int c = wc * 64 + n * 16 + fr;
                bhf[n] = *(const bf16x8*)&Bh[c][fg * 8];
                blf[n] = *(const bf16x8*)&Bl[c][fg * 8];
            }
            #pragma unroll
            for (int m = 0; m < 4; ++m)
                #pragma unroll
                for (int n = 0; n < 4; ++n) {
                    acc[m][n] = __builtin_amdgcn_mfma_f32_16x16x32_bf16(ah[m], bhf[n], acc[m][n], 0, 0, 0);
                    acc[m][n] = __builtin_amdgcn_mfma_f32_16x16x32_bf16(al[m], bhf[n], acc[m][n], 0, 0, 0);
                    acc[m][n] = __builtin_amdgcn_mfma_f32_16x16x32_bf16(ah[m], blf[n], acc[m][n], 0, 0, 0);
                }
        }
    }

    #pragma unroll
    for (int n = 0; n < 4; ++n) {
        int c = col0 + wc * 64 + n * 16 + fr;
        float bv = bias ? bias[c] : 0.f;
        #pragma unroll
        for (int m = 0; m < 4; ++m) {
            int rbase = row0 + wr * 64 + m * 16 + fg * 4;
            #pragma unroll
            for (int i = 0; i < 4; ++i) {
                int r = rbase + i;
                if (r < M) {
                    float v = acc[m][n][i] + bv;
                    if (do_relu) v = fmaxf(v, 0.f);
                    C[(size_t)r * N + c] = v;
                }
            }
        }
    }
}

// ---------------- twin L1 + both rowdots, fused, MFMA ----------------
// s1[r] = dot( relu(X[r]@W + bias), P[r] );  s0[r] = dot(X[r], Q[r])
// X = P1t, P = P2, Q = P1. Internal col-loop (2x128) so each block owns rows.
__global__ __launch_bounds__(256, 2) void gemm_rowdot_mfma(
    const float* __restrict__ X,
    const unsigned short* __restrict__ Wh, const unsigned short* __restrict__ Wl,
    const float* __restrict__ bias,
    const float* __restrict__ P, const float* __restrict__ Q,
    float* __restrict__ s0g, float* __restrict__ s1g, int M)
{
    __shared__ unsigned short Ah[128][40];
    __shared__ unsigned short Al[128][40];
    __shared__ unsigned short Bh[128][40];
    __shared__ unsigned short Bl[128][40];
    __shared__ float srow[128];

    int tid = threadIdx.x;
    int lane = tid & 63;
    int w = tid >> 6;
    int wr = w >> 1, wc = w & 1;
    int row0 = blockIdx.x * 128;
    int sr = tid >> 1;
    int sk = (tid & 1) * 16;
    int grow = row0 + sr; if (grow >= M) grow = M - 1;
    int fr = lane & 15;
    int fg = lane >> 4;

    const float* Xrow = X + (size_t)grow * NFEAT;
    const float* Qrow = Q + (size_t)grow * NFEAT;

    if (tid < 128) srow[tid] = 0.f;
    float s0part = 0.f;
    float rp[4][4];
    #pragma unroll
    for (int m = 0; m < 4; ++m)
        #pragma unroll
        for (int i = 0; i < 4; ++i) rp[m][i] = 0.f;

    for (int ct = 0; ct < 2; ++ct) {
        int col0 = ct * 128;
        const unsigned short* Whrow = Wh + (size_t)(col0 + sr) * NFEAT;
        const unsigned short* Wlrow = Wl + (size_t)(col0 + sr) * NFEAT;

        f32x4 acc[4][4];
        #pragma unroll
        for (int m = 0; m < 4; ++m)
            #pragma unroll
            for (int n = 0; n < 4; ++n)
                acc[m][n] = (f32x4)(0.f);

        for (int k0 = 0; k0 < NFEAT; k0 += 32) {
            unsigned short hh[16], ll[16];
            #pragma unroll
            for (int q = 0; q < 4; ++q) {
                float4 v = *(const float4*)(Xrow + k0 + sk + q * 4);
                if (ct == 0) {
                    float4 qv = *(const float4*)(Qrow + k0 + sk + q * 4);
                    s0part += v.x * qv.x + v.y * qv.y + v.z * qv.z + v.w * qv.w;
                }
                f2hilo(v.x, hh[q*4+0], ll[q*4+0]);
                f2hilo(v.y, hh[q*4+1], ll[q*4+1]);
                f2hilo(v.z, hh[q*4+2], ll[q*4+2]);
                f2hilo(v.w, hh[q*4+3], ll[q*4+3]);
            }
            us8 bh0 = *(const us8*)(Whrow + k0 + sk);
            us8 bh1 = *(const us8*)(Whrow + k0 + sk + 8);
            us8 bl0 = *(const us8*)(Wlrow + k0 + sk);
            us8 bl1 = *(const us8*)(Wlrow + k0 + sk + 8);
            __syncthreads();
            *(us8*)&Ah[sr][sk]     = *(us8*)&hh[0];
            *(us8*)&Ah[sr][sk + 8] = *(us8*)&hh[8];
            *(us8*)&Al[sr][sk]     = *(us8*)&ll[0];
            *(us8*)&Al[sr][sk + 8] = *(us8*)&ll[8];
            *(us8*)&Bh[sr][sk]     = bh0;
            *(us8*)&Bh[sr][sk + 8] = bh1;
            *(us8*)&Bl[sr][sk]     = bl0;
            *(us8*)&Bl[sr][sk + 8] = bl1;
            __syncthreads();

            bf16x8 ah[4], al[4], bhf[4], blf[4];
            #pragma unroll
            for (int m = 0; m < 4; ++m) {
                int r = wr * 64 + m * 16 + fr;
                ah[m] = *(const bf16x8*)&Ah[r][fg * 8];
                al[m] = *(const bf16x8*)&Al[r][fg * 8];
            }
            #pragma unroll
            for (int n = 0; n < 4; ++n) {
                int c = wc * 64 + n * 16 + fr;
                bhf[n] = *(const bf16x8*)&Bh[c][fg * 8];
                blf[n] = *(const bf16x8*)&Bl[c][fg * 8];
            }
            #pragma unroll
            for (int m = 0; m < 4; ++m)
                #pragma unroll
                for (int n = 0; n < 4; ++n) {
                    acc[m][n] = __builtin_amdgcn_mfma_f32_16x16x32_bf16(ah[m], bhf[n], acc[m][n], 0, 0, 0);
                    acc[m][n] = __builtin_amdgcn_mfma_f32_16x16x32_bf16(al[m], bhf[n], acc[m][n], 0, 0, 0);
                    acc[m][n] = __builtin_amdgcn_mfma_f32_16x16x32_bf16(ah[m], blf[n], acc[m][n], 0, 0, 0);
                }
        }

        // fold this col-half into the row dot-products
        #pragma unroll
        for (int n = 0; n < 4; ++n) {
            int c = col0 + wc * 64 + n * 16 + fr;
            float bv = bias[c];
            #pragma unroll
            for (int m = 0; m < 4; ++m) {
                #pragma unroll
                for (int i = 0; i < 4; ++i) {
                    int r = row0 + wr * 64 + m * 16 + fg * 4 + i;
                    if (r < M) {
                        float v = fmaxf(acc[m][n][i] + bv, 0.f);
                        rp[m][i] += v * P[(size_t)r * NFEAT + c];
                    }
                }
            }
        }
    }

    // reduce rp over the 16 fr lanes
    #pragma unroll
    for (int o = 1; o < 16; o <<= 1) {
        #pragma unroll
        for (int m = 0; m < 4; ++m)
            #pragma unroll
            for (int i = 0; i < 4; ++i)
                rp[m][i] += __shfl_xor(rp[m][i], o);
    }
    if ((lane & 15) == 0) {
        #pragma unroll
        for (int m = 0; m < 4; ++m)
            #pragma unroll
            for (int i = 0; i < 4; ++i)
                atomicAdd(&srow[wr * 64 + m * 16 + fg * 4 + i], rp[m][i]);
    }
    // s0: two staging threads per row
    s0part += __shfl_xor(s0part, 1);
    if ((tid & 1) == 0 && row0 + sr < M) s0g[row0 + sr] = s0part;
    __syncthreads();
    if (tid < 128 && row0 + tid < M) s1g[row0 + tid] = srow[tid];
}

// ---------------- head GEMM with fused combine ----------------
// logits = (a0*P1 + a1*P2) @ outW + outb  ; N = 128
__global__ __launch_bounds__(256, 2) void gemm_head(
    const float* __restrict__ P1, const float* __restrict__ P2,
    const float* __restrict__ alpha,
    const unsigned short* __restrict__ Wh, const unsigned short* __restrict__ Wl,
    const float* __restrict__ bias,
    float* __restrict__ C, int M, int N)
{
    __shared__ unsigned short Ah[128][40];
    __shared__ unsigned short Al[128][40];
    __shared__ unsigned short Bh[128][40];
    __shared__ unsigned short Bl[128][40];

    int tid = threadIdx.x;
    int lane = tid & 63;
    int w = tid >> 6;
    int wr = w >> 1, wc = w & 1;
    int row0 = blockIdx.x * 128;
    int sr = tid >> 1;
    int sk = (tid & 1) * 16;
    int grow = row0 + sr; if (grow >= M) grow = M - 1;
    int fr = lane & 15;
    int fg = lane >> 4;

    const float* P1row = P1 + (size_t)grow * NFEAT;
    const float* P2row = P2 + (size_t)grow * NFEAT;
    float a0 = alpha[grow], a1 = alpha[M + grow];

    f32x4 acc[4][4];
    #pragma unroll
    for (int m = 0; m < 4; ++m)
        #pragma unroll
        for (int n = 0; n < 4; ++n)
            acc[m][n] = (f32x4)(0.f);

    const unsigned short* Whrow = Wh + (size_t)sr * NFEAT;
    const unsigned short* Wlrow = Wl + (size_t)sr * NFEAT;

    for (int k0 = 0; k0 < NFEAT; k0 += 32) {
        unsigned short hh[16], ll[16];
        #pragma unroll
        for (int q = 0; q < 4; ++q) {
            float4 v1 = *(const float4*)(P1row + k0 + sk + q * 4);
            float4 v2 = *(const float4*)(P2row + k0 + sk + q * 4);
            float4 v = make_float4(a0 * v1.x + a1 * v2.x, a0 * v1.y + a1 * v2.y,
                                   a0 * v1.z + a1 * v2.z, a0 * v1.w + a1 * v2.w);
            f2hilo(v.x, hh[q*4+0], ll[q*4+0]);
            f2hilo(v.y, hh[q*4+1], ll[q*4+1]);
            f2hilo(v.z, hh[q*4+2], ll[q*4+2]);
            f2hilo(v.w, hh[q*4+3], ll[q*4+3]);
        }
        us8 bh0 = *(const us8*)(Whrow + k0 + sk);
        us8 bh1 = *(const us8*)(Whrow + k0 + sk + 8);
        us8 bl0 = *(const us8*)(Wlrow + k0 + sk);
        us8 bl1 = *(const us8*)(Wlrow + k0 + sk + 8);
        __syncthreads();
        *(us8*)&Ah[sr][sk]     = *(us8*)&hh[0];
        *(us8*)&Ah[sr][sk + 8] = *(us8*)&hh[8];
        *(us8*)&Al[sr][sk]     = *(us8*)&ll[0];
        *(us8*)&Al[sr][sk + 8] = *(us8*)&ll[8];
        *(us8*)&Bh[sr][sk]     = bh0;
        *(us8*)&Bh[sr][sk + 8] = bh1;
        *(us8*)&Bl[sr][sk]     = bl0;
        *(us8*)&Bl[sr][sk + 8] = bl1;
        __syncthreads();

        bf16x8 ah[4], al[4], bhf[4], blf[4];
        #pragma unroll
        for (int m = 0; m < 4; ++m) {
            int r = wr * 64 + m * 16 + fr;
            ah[m] = *(const bf16x8*)&Ah[r][fg * 8];
            al[m] = *(const bf16x8*)&Al[r][fg * 8];
        }
        #pragma unroll
        for (int n = 0; n < 4; ++n) {
            int c = wc * 64 + n * 16 + fr;
            bhf[n] = *(const bf16x8*)&Bh[c][fg * 8];
            blf[n] = *(const bf16x8*)&Bl[c][fg * 8];
        }
        #pragma unroll
        for (int m = 0; m < 4; ++m)
            #pragma unroll
            for (int n = 0; n < 4; ++n) {
                acc[m][n] = __builtin_amdgcn_mfma_f32_16x16x32_bf16(ah[m], bhf[n], acc[m][n], 0, 0, 0);
                acc[m][n] = __builtin_amdgcn_mfma_f32_16x16x32_bf16(al[m], bhf[n], acc[m][n], 0, 0, 0);
                acc[m][n] = __builtin_amdgcn_mfma_f32_16x16x32_bf16(ah[m], blf[n], acc[m][n], 0, 0, 0);
            }
    }

    #pragma unroll
    for (int n = 0; n < 4; ++n) {
        int c = wc * 64 + n * 16 + fr;
        if (c >= N) continue;
        float bv = bias[c];
        #pragma unroll
        for (int m = 0; m < 4; ++m) {
            int rbase = row0 + wr * 64 + m * 16 + fg * 4;
            #pragma unroll
            for (int i = 0; i < 4; ++i) {
                int r = rbase + i;
                if (r < M) C[(size_t)r * N + c] = acc[m][n][i] + bv;
            }
        }
    }
}

extern "C" void kernel_launch(void* const* d_in, const int* in_sizes, int n_in,
                              void* d_out, int out_size, void* d_ws, size_t ws_size,
                              hipStream_t stream)
{
    const float* x_paper    = (const float*)d_in[0];
    const float* emb_author = (const float*)d_in[1];
    const float* W0rp = (const float*)d_in[2];
    const float* b0rp = (const float*)d_in[3];
    const float* W0ra = (const float*)d_in[4];
    const float* b0ra = (const float*)d_in[5];
    const float* W0w  = (const float*)d_in[6];
    const float* W0rev= (const float*)d_in[7];
    const float* W0c  = (const float*)d_in[8];
    const float* W1rp = (const float*)d_in[9];
    const float* b1rp = (const float*)d_in[10];
    const float* W1w  = (const float*)d_in[13];
    const float* W1c  = (const float*)d_in[15];
    const float* outW = (const float*)d_in[16];
    const float* outb = (const float*)d_in[17];
    const int* w_src = (const int*)d_in[18];
    const int* w_dst = (const int*)d_in[19];
    const int* r_src = (const int*)d_in[20];
    const int* r_dst = (const int*)d_in[21];
    const int* c_src = (const int*)d_in[22];
    const int* c_dst = (const int*)d_in[23];

    const int NP = in_sizes[0] / NFEAT;   // 50000
    const int NA = in_sizes[1] / NFEAT;   // 50000
    const int NC = in_sizes[17];          // 128
    const int nEw = in_sizes[18], nEr = in_sizes[20], nEc = in_sizes[22];

    // ---- workspace (~164 MB): 3 big fp32 buffers + planes + CSR ----
    size_t NB = (size_t)(NP > NA ? NP : NA) * NFEAT;
    float* Z0 = (float*)d_ws;
    float* Z1 = Z0 + NB;
    float* Z2 = Z1 + NB;
    float* s0 = Z2 + NB;            // NP
    float* s1 = s0 + NP;            // NP
    unsigned short* Wt = (unsigned short*)(s1 + NP);   // 11 slots x 131072 ushorts
    #define WT_HI(i) (Wt + (size_t)(i) * 131072)
    #define WT_LO(i) (Wt + (size_t)(i) * 131072 + 65536)
    int* degW = (int*)(Wt + 11 * 131072);
    int* degR = degW + NP;
    int* degC = degR + NA;
    int* curW = degC + NP;
    int* curR = curW + NP;
    int* curC = curR + NA;
    int* offW = curC + NP;          // NP+1
    int* offR = offW + NP + 1;      // NA+1
    int* offC = offR + NA + 1;      // NP+1
    int* bsW  = offC + NP + 1;      // 256
    int* bsR  = bsW + 256;
    int* bsC  = bsR + 256;
    int* listW = bsC + 256;         // nEw
    int* listR = listW + nEw;       // nEr
    int* listC = listR + nEr;       // nEc

    float* out   = (float*)d_out;                 // logits [NP, NC]
    float* alpha = out + (size_t)NP * NC;         // [2, NP]

    // ---- CSR build ----
    hipMemsetAsync(degW, 0, (size_t)2 * (NP + NA + NP) * sizeof(int), stream);
    deg_int_kernel<<<(nEw + 255) / 256, 256, 0, stream>>>(w_dst, degW, nEw);
    deg_int_kernel<<<(nEr + 255) / 256, 256, 0, stream>>>(r_dst, degR, nEr);
    deg_int_kernel<<<(nEc + 255) / 256, 256, 0, stream>>>(c_dst, degC, nEc);

    int nbP = (NP + 255) / 256, nbA = (NA + 255) / 256;
    scan_p1<<<nbP, 256, 0, stream>>>(degW, NP, offW, bsW);
    scan_p1<<<nbA, 256, 0, stream>>>(degR, NA, offR, bsR);
    scan_p1<<<nbP, 256, 0, stream>>>(degC, NP, offC, bsC);
    scan_p2<<<3, 256, 0, stream>>>(bsW, nbP, bsR, nbA, bsC, nbP);
    scan_p3<<<nbP, 256, 0, stream>>>(NP, offW, bsW);
    scan_p3<<<nbA, 256, 0, stream>>>(NA, offR, bsR);
    scan_p3<<<nbP, 256, 0, stream>>>(NP, offC, bsC);

    fill_csr_kernel<<<(nEw + 255) / 256, 256, 0, stream>>>(w_src, w_dst, nEw, offW, curW, listW);
    fill_csr_kernel<<<(nEr + 255) / 256, 256, 0, stream>>>(r_src, r_dst, nEr, offR, curR, listR);
    fill_csr_kernel<<<(nEc + 255) / 256, 256, 0, stream>>>(c_src, c_dst, nEc, offC, curC, listC);

    // ---- weight conversion (slots: 0=W0rp 1=W0w 2=W0c 3=W0ra 4=W0rev 5=W1rp 6=W1w 7=W1c 8=Wc0 9=Wc1 10=outW) ----
    cvt8_kernel<<<dim3(256, 8), 256, 0, stream>>>(W0rp, W0w, W0c, W0ra, W0rev, W1rp, W1w, W1c, Wt);
    cvtfold_kernel<<<dim3(256, 2), 256, 0, stream>>>(W0rp, W0w, W0c, W1rp, W1w, W1c, Wt);
    cvtrect_kernel<<<128, 256, 0, stream>>>(outW, Wt);

    dim3 blk(256);
    dim3 gP((NP + 127) / 128, 2);     // N=256
    dim3 gA((NA + 127) / 128, 2);
    dim3 g1((NP + 127) / 128);
    int nodeP = (NP + 3) / 4, nodeA = (NA + 3) / 4;

    // --- L0: aggregate raw features, then one fused GEMM per node type ---
    agg_csr_kernel<<<nodeP, blk, 0, stream>>>(emb_author, offW, listW, Z0, 0, 0, NP);  // Mw
    agg_csr_kernel<<<nodeP, blk, 0, stream>>>(x_paper,    offC, listC, Z1, 0, 0, NP);  // Mc
    {   // P1 = relu([Xp|Mw|Mc] @ [W0rp;W0w;W0c] + b0rp) -> Z2
        Seg3 sp = {x_paper, Z0, Z1, WT_HI(0), WT_LO(0), WT_HI(1), WT_LO(1), WT_HI(2), WT_LO(2)};
        gemm_ms<<<gP, blk, 0, stream>>>(sp, 3, b0rp, 1, Z2, NP, NFEAT);
    }
    agg_csr_kernel<<<nodeA, blk, 0, stream>>>(x_paper, offR, listR, Z0, 0, 0, NA);     // Mr
    {   // Au1 = relu([Xa|Mr] @ [W0ra;W0rev] + b0ra) -> Z1
        Seg3 sp = {emb_author, Z0, nullptr, WT_HI(3), WT_LO(3), WT_HI(4), WT_LO(4), nullptr, nullptr};
        gemm_ms<<<gA, blk, 0, stream>>>(sp, 2, b0ra, 1, Z1, NA, NFEAT);
    }

    // --- L1 paper ---
    agg_csr_kernel<<<nodeP, blk, 0, stream>>>(Z1, offW, listW, Z0, 0, 0, NP);          // Mw2 = mean_w(Au1)
    {   // P2pre = [P1|Mw2] @ [W1rp;W1w] + b1rp -> Z1 (Au1 consumed)
        Seg3 sp = {Z2, Z0, nullptr, WT_HI(5), WT_LO(5), WT_HI(6), WT_LO(6), nullptr, nullptr};
        gemm_ms<<<gP, blk, 0, stream>>>(sp, 2, b1rp, 0, Z1, NP, NFEAT);
    }
    {   // T = P1 @ W1c -> Z0 (Mw2 consumed)
        Seg3 sp = {Z2, nullptr, nullptr, WT_HI(7), WT_LO(7), nullptr, nullptr, nullptr, nullptr};
        gemm_ms<<<gP, blk, 0, stream>>>(sp, 1, nullptr, 0, Z0, NP, NFEAT);
    }
    agg_csr_kernel<<<nodeP, blk, 0, stream>>>(Z0, offC, listC, Z1, 1, 1, NP);          // P2 = relu(P2pre + mean_c(T))

    // --- twin path + rowdots ---
    {   // P1t = relu(Xp @ Wc0 + b0rp) -> Z0
        Seg3 sp = {x_paper, nullptr, nullptr, WT_HI(8), WT_LO(8), nullptr, nullptr, nullptr, nullptr};
        gemm_ms<<<gP, blk, 0, stream>>>(sp, 1, b0rp, 1, Z0, NP, NFEAT);
    }
    // s1 = P2 . relu(P1t@Wc1+b1rp) ; s0 = P1 . P1t
    gemm_rowdot_mfma<<<g1, blk, 0, stream>>>(Z0, WT_HI(9), WT_LO(9), b1rp, Z1, Z2, s0, s1, NP);

    // --- summarize + head ---
    alpha_kernel<<<(NP + 255) / 256, blk, 0, stream>>>(s0, s1, alpha, NP);
    gemm_head<<<g1, blk, 0, stream>>>(Z2, Z1, alpha, WT_HI(10), WT_LO(10), outb, out, NP, NC);
}